// Round 1
// baseline (895.032 us; speedup 1.0000x reference)
//
#include <hip/hip_runtime.h>
#include <hip/hip_bf16.h>
#include <stdint.h>

// Decoder triangular GEMM: out[b,i,a] = sum_{l<=i} sum_f x[b,l,f] * W_i[l,f,a]
// Strategy: bf16 MFMA (memory-bound, ~160us floor) instead of fp32 VALU
// (compute-bound, ~400us floor). W converted fp32->bf16 in registers during
// LDS staging (read once from HBM, never re-materialized).

#define BSZ   128
#define NLAY  12
#define DF    4096
#define DA    768
#define NTILE 6                 // 768 / 128
#define NSLAB 78                // sum_{i=0..11} (i+1)
#define NTASK (NSLAB * NTILE)   // 468
#define BM    128
#define BN    128
#define BK    64
#define LDP   72                // padded K pitch (elements) -> 2-way-max bank conflicts

typedef __attribute__((ext_vector_type(8))) short bf16x8;
typedef __attribute__((ext_vector_type(4))) float f32x4;

struct WPtrs { const float* w[12]; };

__device__ __forceinline__ uint16_t f2bf_rne(float f) {
    uint32_t u = __builtin_bit_cast(uint32_t, f);
    u += 0x7fffu + ((u >> 16) & 1u);   // round-nearest-even
    return (uint16_t)(u >> 16);
}

// ---- Phase 0: convert x [128,12,4096] fp32 -> bf16 in ws ----
__global__ void cvt_x_kernel(const float* __restrict__ x, uint16_t* __restrict__ xb, int n4) {
    int t = blockIdx.x * blockDim.x + threadIdx.x;
    if (t >= n4) return;
    float4 v = ((const float4*)x)[t];
    ushort4 o;
    o.x = f2bf_rne(v.x); o.y = f2bf_rne(v.y);
    o.z = f2bf_rne(v.z); o.w = f2bf_rne(v.w);
    ((ushort4*)xb)[t] = o;
}

// ---- Phase 1: one block per (slab, n-tile): C_partial = x_bf[:,l,:] * bf16(W_i[l,:,ntile]) ----
template<bool XBF, bool PARTIAL>
__launch_bounds__(256, 2)
__global__ void tri_gemm(const void* __restrict__ xsrc, WPtrs wp, float* __restrict__ dst) {
    __shared__ uint16_t Al[BM * LDP];
    __shared__ uint16_t Bl[BN * LDP];

    const int task = blockIdx.x;
    const int slab = task / NTILE;
    const int nt   = task - slab * NTILE;
    int i = 0;
    #pragma unroll
    for (int j = 0; j < 12; ++j) { if (slab >= ((j + 1) * (j + 2)) / 2) i = j + 1; }
    const int l = slab - (i * (i + 1)) / 2;
    const float* __restrict__ W = wp.w[i] + (size_t)l * DF * DA + nt * BN;

    const int tid  = threadIdx.x;
    const int lane = tid & 63;
    const int wave = tid >> 6;
    const int wm = wave >> 1, wn = wave & 1;

    // A staging: thread covers rows {ar, ar+32, ar+64, ar+96} at col ac (8 bf16)
    const int ar = tid >> 3;          // 0..31
    const int ac = (tid & 7) * 8;     // 0..56
    // B staging: thread covers two 4k x 4n blocks: (bkg, bng) and (bkg+8, bng)
    const int bng = tid & 31;         // 0..31  (n-group of 4)
    const int bkg = tid >> 5;         // 0..7   (k-group of 4)

    f32x4 acc[4][4];
    #pragma unroll
    for (int a = 0; a < 4; ++a)
        #pragma unroll
        for (int b = 0; b < 4; ++b) acc[a][b] = (f32x4){0.f, 0.f, 0.f, 0.f};

    uint4  aReg[4];
    float4 aRegF[8];
    float4 bReg[2][4];

    const uint16_t* __restrict__ xb = (const uint16_t*)xsrc;
    const float*    __restrict__ xf = (const float*)xsrc;
    const size_t xoff = (size_t)l * DF;         // row stride is NLAY*DF

    auto loadAB = [&](int k0) {
        if constexpr (XBF) {
            #pragma unroll
            for (int s = 0; s < 4; ++s) {
                int row = ar + 32 * s;
                aReg[s] = *(const uint4*)(xb + (size_t)row * (NLAY * DF) + xoff + k0 + ac);
            }
        } else {
            #pragma unroll
            for (int s = 0; s < 4; ++s) {
                int row = ar + 32 * s;
                const float* p = xf + (size_t)row * (NLAY * DF) + xoff + k0 + ac;
                aRegF[2 * s]     = *(const float4*)(p);
                aRegF[2 * s + 1] = *(const float4*)(p + 4);
            }
        }
        #pragma unroll
        for (int blk = 0; blk < 2; ++blk) {
            int kg = bkg + 8 * blk;
            #pragma unroll
            for (int dk = 0; dk < 4; ++dk)
                bReg[blk][dk] = *(const float4*)(W + (size_t)(k0 + kg * 4 + dk) * DA + bng * 4);
        }
    };

    auto storeAB = [&]() {
        if constexpr (XBF) {
            #pragma unroll
            for (int s = 0; s < 4; ++s) {
                int row = ar + 32 * s;
                *(uint4*)(&Al[row * LDP + ac]) = aReg[s];
            }
        } else {
            #pragma unroll
            for (int s = 0; s < 4; ++s) {
                int row = ar + 32 * s;
                float4 v0 = aRegF[2 * s], v1 = aRegF[2 * s + 1];
                ushort4 lo, hi;
                lo.x = f2bf_rne(v0.x); lo.y = f2bf_rne(v0.y); lo.z = f2bf_rne(v0.z); lo.w = f2bf_rne(v0.w);
                hi.x = f2bf_rne(v1.x); hi.y = f2bf_rne(v1.y); hi.z = f2bf_rne(v1.z); hi.w = f2bf_rne(v1.w);
                *(ushort4*)(&Al[row * LDP + ac])     = lo;
                *(ushort4*)(&Al[row * LDP + ac + 4]) = hi;
            }
        }
        // B: in-register 4x4 transpose, write 4 bf16 contiguous-in-k per n row
        #pragma unroll
        for (int blk = 0; blk < 2; ++blk) {
            int kg = bkg + 8 * blk;
            #pragma unroll
            for (int dn = 0; dn < 4; ++dn) {
                ushort4 o;
                o.x = f2bf_rne(((const float*)&bReg[blk][0])[dn]);
                o.y = f2bf_rne(((const float*)&bReg[blk][1])[dn]);
                o.z = f2bf_rne(((const float*)&bReg[blk][2])[dn]);
                o.w = f2bf_rne(((const float*)&bReg[blk][3])[dn]);
                *(ushort4*)(&Bl[(bng * 4 + dn) * LDP + kg * 4]) = o;
            }
        }
    };

    loadAB(0);
    #pragma unroll 1
    for (int it = 0; it < DF / BK; ++it) {
        __syncthreads();           // previous iter's LDS fully consumed
        storeAB();
        __syncthreads();
        if (it + 1 < DF / BK) loadAB((it + 1) * BK);   // in flight during MFMA

        #pragma unroll
        for (int ks = 0; ks < 2; ++ks) {
            bf16x8 af[4], bfr[4];
            const int krd = ks * 32 + (lane >> 4) * 8;
            #pragma unroll
            for (int mi = 0; mi < 4; ++mi)
                af[mi] = *(const bf16x8*)(&Al[(wm * 64 + mi * 16 + (lane & 15)) * LDP + krd]);
            #pragma unroll
            for (int ni = 0; ni < 4; ++ni)
                bfr[ni] = *(const bf16x8*)(&Bl[(wn * 64 + ni * 16 + (lane & 15)) * LDP + krd]);
            #pragma unroll
            for (int mi = 0; mi < 4; ++mi)
                #pragma unroll
                for (int ni = 0; ni < 4; ++ni)
                    acc[mi][ni] = __builtin_amdgcn_mfma_f32_16x16x32_bf16(af[mi], bfr[ni], acc[mi][ni], 0, 0, 0);
        }
    }

    // Epilogue. C/D layout: col = lane&15, row = (lane>>4)*4 + reg  [m89-verified]
    if constexpr (PARTIAL) {
        float* out = dst + (size_t)task * (BM * BN);
        #pragma unroll
        for (int mi = 0; mi < 4; ++mi)
            #pragma unroll
            for (int ni = 0; ni < 4; ++ni) {
                const int col  = wn * 64 + ni * 16 + (lane & 15);
                const int row0 = wm * 64 + mi * 16 + (lane >> 4) * 4;
                #pragma unroll
                for (int r = 0; r < 4; ++r)
                    out[(size_t)(row0 + r) * BN + col] = acc[mi][ni][r];
            }
    } else {
        #pragma unroll
        for (int mi = 0; mi < 4; ++mi)
            #pragma unroll
            for (int ni = 0; ni < 4; ++ni) {
                const int col  = nt * BN + wn * 64 + ni * 16 + (lane & 15);
                const int row0 = wm * 64 + mi * 16 + (lane >> 4) * 4;
                #pragma unroll
                for (int r = 0; r < 4; ++r)
                    atomicAdd(&dst[(size_t)(row0 + r) * (NLAY * DA) + i * DA + col], acc[mi][ni][r]);
            }
    }
}

// ---- Phase 2: out[b,i,a] = sum_{l<=i} P[(tri(i)+l)*6 + a/128][b][a%128] ----
__global__ void reduce_partials(const float* __restrict__ P, float* __restrict__ out, int total) {
    int t = blockIdx.x * blockDim.x + threadIdx.x;
    if (t >= total) return;
    const int b  = t / (NLAY * DA);
    const int r  = t - b * (NLAY * DA);
    const int i  = r / DA;
    const int a  = r - i * DA;
    const int nt = a >> 7;
    const int ac = a & 127;
    const int tri = (i * (i + 1)) / 2;
    float s = 0.f;
    for (int l = 0; l <= i; ++l)
        s += P[(size_t)((tri + l) * NTILE + nt) * (BM * BN) + (size_t)b * BN + ac];
    out[t] = s;
}

__global__ void zero_kernel(float* __restrict__ p, int n) {
    int t = blockIdx.x * blockDim.x + threadIdx.x;
    if (t < n) p[t] = 0.f;
}

extern "C" void kernel_launch(void* const* d_in, const int* in_sizes, int n_in,
                              void* d_out, int out_size, void* d_ws, size_t ws_size,
                              hipStream_t stream) {
    const float* x = (const float*)d_in[0];
    WPtrs wp;
    for (int i = 0; i < 12; ++i) wp.w[i] = (const float*)d_in[1 + i];
    float* out = (float*)d_out;

    const size_t xbBytes = (size_t)BSZ * NLAY * DF * 2;        // 12,582,912
    const size_t pBytes  = (size_t)NTASK * BM * BN * 4;        // 30,670,848
    const int total = BSZ * NLAY * DA;                         // 1,179,648

    if (ws_size >= xbBytes + pBytes) {
        uint16_t* xb = (uint16_t*)d_ws;
        float* P = (float*)((char*)d_ws + xbBytes);
        const int n4 = BSZ * NLAY * DF / 4;
        cvt_x_kernel<<<(n4 + 255) / 256, 256, 0, stream>>>(x, xb, n4);
        tri_gemm<true, true><<<NTASK, 256, 0, stream>>>(xb, wp, P);
        reduce_partials<<<(total + 255) / 256, 256, 0, stream>>>(P, out, total);
    } else {
        zero_kernel<<<(total + 255) / 256, 256, 0, stream>>>(out, total);
        tri_gemm<false, false><<<NTASK, 256, 0, stream>>>(x, wp, out);
    }
}